// Round 1
// baseline (503.693 us; speedup 1.0000x reference)
//
#include <hip/hip_runtime.h>
#include <math.h>

#define NB 32
#define NI 2048
#define NO 64
#define NP 16
#define EPSF 1e-9f

__device__ __forceinline__ float wave_max64(float v) {
#pragma unroll
    for (int off = 32; off > 0; off >>= 1) v = fmaxf(v, __shfl_xor(v, off));
    return v;
}
__device__ __forceinline__ float wave_sum64(float v) {
#pragma unroll
    for (int off = 32; off > 0; off >>= 1) v += __shfl_xor(v, off);
    return v;
}

// ---------------------------------------------------------------------------
// Pass 0: sum votes over i  ->  sum_part[b,o,p]   (mean for Mu init)
// grid (NI/64, NB), block 256 (4 waves). lane = o; wave handles i0+wave, step 4.
// ---------------------------------------------------------------------------
__global__ __launch_bounds__(256) void mean_accum_kernel(
        const float* __restrict__ votes, float* __restrict__ sum_part) {
    const int b    = blockIdx.y;
    const int i0   = blockIdx.x * 64;
    const int wave = threadIdx.x >> 6;
    const int lane = threadIdx.x & 63;  // o

    float s[NP];
#pragma unroll
    for (int p = 0; p < NP; ++p) s[p] = 0.f;

    for (int i = i0 + wave; i < i0 + 64; i += 4) {
        const float4* vp = reinterpret_cast<const float4*>(
            votes + (((size_t)b * NI + i) * NO + lane) * NP);
        float4 v0 = vp[0], v1 = vp[1], v2 = vp[2], v3 = vp[3];
        s[0] += v0.x;  s[1] += v0.y;  s[2] += v0.z;  s[3] += v0.w;
        s[4] += v1.x;  s[5] += v1.y;  s[6] += v1.z;  s[7] += v1.w;
        s[8] += v2.x;  s[9] += v2.y;  s[10] += v2.z; s[11] += v2.w;
        s[12] += v3.x; s[13] += v3.y; s[14] += v3.z; s[15] += v3.w;
    }

    __shared__ float red[4][NO * NP];
#pragma unroll
    for (int p = 0; p < NP; ++p) red[wave][lane * NP + p] = s[p];
    __syncthreads();
    for (int e = threadIdx.x; e < NO * NP; e += 256) {
        float v = red[0][e] + red[1][e] + red[2][e] + red[3][e];
        atomicAdd(&sum_part[(size_t)b * NO * NP + e], v);
    }
}

// ---------------------------------------------------------------------------
// Mu init = l2_normalize(sum / I); A init = 1/O.  grid NB, block NO.
// ---------------------------------------------------------------------------
__global__ void mean_final_kernel(const float* __restrict__ sum_part,
                                  float* __restrict__ Mu, float* __restrict__ A) {
    const int b = blockIdx.x;
    const int o = threadIdx.x;  // 64 threads
    const float inv_I = 1.0f / (float)NI;
    float m[NP];
    float ssq = 0.f;
#pragma unroll
    for (int p = 0; p < NP; ++p) {
        m[p] = sum_part[((size_t)b * NO + o) * NP + p] * inv_I;
        ssq += m[p] * m[p];
    }
    float inv = rsqrtf(fmaxf(ssq, 1e-12f));
#pragma unroll
    for (int p = 0; p < NP; ++p)
        Mu[((size_t)b * NO + o) * NP + p] = m[p] * inv;
    A[b * NO + o] = 1.0f / (float)NO;
}

// ---------------------------------------------------------------------------
// One routing iteration (fused dot/softmax/accumulate).
// grid (NI/64, NB), block 256. lane = o.
// ---------------------------------------------------------------------------
__global__ __launch_bounds__(256) void iter_accum_kernel(
        const float* __restrict__ votes, const float* __restrict__ act,
        const float* __restrict__ Mu, const float* __restrict__ A,
        float* __restrict__ num_part, float* __restrict__ den_part,
        float* __restrict__ rsum_part) {
    const int b    = blockIdx.y;
    const int i0   = blockIdx.x * 64;
    const int wave = threadIdx.x >> 6;
    const int lane = threadIdx.x & 63;  // o

    float mu[NP];
    {
        const float4* mp = reinterpret_cast<const float4*>(
            Mu + ((size_t)b * NO + lane) * NP);
        float4 m0 = mp[0], m1 = mp[1], m2 = mp[2], m3 = mp[3];
        mu[0] = m0.x;  mu[1] = m0.y;  mu[2] = m0.z;  mu[3] = m0.w;
        mu[4] = m1.x;  mu[5] = m1.y;  mu[6] = m1.z;  mu[7] = m1.w;
        mu[8] = m2.x;  mu[9] = m2.y;  mu[10] = m2.z; mu[11] = m2.w;
        mu[12] = m3.x; mu[13] = m3.y; mu[14] = m3.z; mu[15] = m3.w;
    }
    const float Ao   = A[b * NO + lane];
    const float logA = logf(Ao + EPSF);

    float num[NP];
#pragma unroll
    for (int p = 0; p < NP; ++p) num[p] = 0.f;
    float den = 0.f, rs = 0.f;

    for (int i = i0 + wave; i < i0 + 64; i += 4) {
        const float4* vp = reinterpret_cast<const float4*>(
            votes + (((size_t)b * NI + i) * NO + lane) * NP);
        float4 v0 = vp[0], v1 = vp[1], v2 = vp[2], v3 = vp[3];

        float ssq = v0.x * v0.x + v0.y * v0.y + v0.z * v0.z + v0.w * v0.w
                  + v1.x * v1.x + v1.y * v1.y + v1.z * v1.z + v1.w * v1.w
                  + v2.x * v2.x + v2.y * v2.y + v2.z * v2.z + v2.w * v2.w
                  + v3.x * v3.x + v3.y * v3.y + v3.z * v3.z + v3.w * v3.w;
        float dt  = v0.x * mu[0]  + v0.y * mu[1]  + v0.z * mu[2]  + v0.w * mu[3]
                  + v1.x * mu[4]  + v1.y * mu[5]  + v1.z * mu[6]  + v1.w * mu[7]
                  + v2.x * mu[8]  + v2.y * mu[9]  + v2.z * mu[10] + v2.w * mu[11]
                  + v3.x * mu[12] + v3.y * mu[13] + v3.z * mu[14] + v3.w * mu[15];

        float dn = dt * rsqrtf(fmaxf(ssq, 1e-12f));
        float cv = 1.0f - dn * dn;                    // BETA_V = 1
        float a  = act[b * NI + i];                   // wave-uniform broadcast
        float lp = logA - cv - fabsf(a - Ao);         // BETA_A = 1

        // softmax over the 64 o's (one per lane)
        float mx = wave_max64(lp);
        float e  = __expf(lp - mx);
        float R  = e / wave_sum64(e);

        rs  += R * a;
        den += R;
        num[0]  += R * v0.x; num[1]  += R * v0.y; num[2]  += R * v0.z; num[3]  += R * v0.w;
        num[4]  += R * v1.x; num[5]  += R * v1.y; num[6]  += R * v1.z; num[7]  += R * v1.w;
        num[8]  += R * v2.x; num[9]  += R * v2.y; num[10] += R * v2.z; num[11] += R * v2.w;
        num[12] += R * v3.x; num[13] += R * v3.y; num[14] += R * v3.z; num[15] += R * v3.w;
    }

    // block-level reduction of 4 waves, then one atomic set per block
    __shared__ float red[4][NO * 18];
    float* myred = &red[wave][lane * 18];
#pragma unroll
    for (int p = 0; p < NP; ++p) myred[p] = num[p];
    myred[16] = den;
    myred[17] = rs;
    __syncthreads();
    for (int e = threadIdx.x; e < NO * 18; e += 256) {
        float v = red[0][e] + red[1][e] + red[2][e] + red[3][e];
        int o = e / 18;
        int k = e - o * 18;
        if (k < NP)        atomicAdd(&num_part[((size_t)b * NO + o) * NP + k], v);
        else if (k == 16)  atomicAdd(&den_part[b * NO + o], v);
        else               atomicAdd(&rsum_part[b * NO + o], v);
    }
}

// ---------------------------------------------------------------------------
// A_h and Mu_h from partials.  grid NB, block NO (1 wave).
// ---------------------------------------------------------------------------
__global__ void finalize_kernel(const float* __restrict__ num_part,
                                const float* __restrict__ den_part,
                                const float* __restrict__ rsum_part,
                                float* __restrict__ Mu_out,
                                float* __restrict__ A_out) {
    const int b = blockIdx.x;
    const int o = threadIdx.x;  // 64
    float rsv = rsum_part[b * NO + o];
    float tot = wave_sum64(rsv);
    float Anew = rsv / (tot + EPSF);
    Anew = fminf(fmaxf(Anew, EPSF), 1.0f - EPSF);
    A_out[b * NO + o] = Anew;

    float inv_dn = 1.0f / (den_part[b * NO + o] + EPSF);
    float m[NP];
    float ssq = 0.f;
#pragma unroll
    for (int p = 0; p < NP; ++p) {
        m[p] = num_part[((size_t)b * NO + o) * NP + p] * inv_dn;
        ssq += m[p] * m[p];
    }
    float inv = rsqrtf(fmaxf(ssq, 1e-12f));
#pragma unroll
    for (int p = 0; p < NP; ++p)
        Mu_out[((size_t)b * NO + o) * NP + p] = m[p] * inv;
}

// ---------------------------------------------------------------------------
extern "C" void kernel_launch(void* const* d_in, const int* in_sizes, int n_in,
                              void* d_out, int out_size, void* d_ws, size_t ws_size,
                              hipStream_t stream) {
    const float* votes = (const float*)d_in[0];
    const float* act   = (const float*)d_in[1];

    float* Mu_out = (float*)d_out;                     // NB*NO*NP = 32768
    float* A_out  = (float*)d_out + NB * NO * NP;      // NB*NO    = 2048

    float* ws        = (float*)d_ws;
    float* num_part  = ws;                      // 32768
    float* den_part  = ws + 32768;              // 2048
    float* rsum_part = ws + 34816;              // 2048   (contiguous w/ num,den)
    float* Mu        = ws + 36864;              // 32768
    float* A         = ws + 69632;              // 2048

    dim3 grid(NI / 64, NB);
    dim3 blk(256);

    // Pass 0: mean -> Mu init, A init
    hipMemsetAsync(num_part, 0, (size_t)NB * NO * NP * sizeof(float), stream);
    mean_accum_kernel<<<grid, blk, 0, stream>>>(votes, num_part);
    mean_final_kernel<<<NB, NO, 0, stream>>>(num_part, Mu, A);

    // 3 routing iterations
    for (int it = 0; it < 3; ++it) {
        hipMemsetAsync(num_part, 0, (size_t)(NB * NO * NP + 2 * NB * NO) * sizeof(float), stream);
        iter_accum_kernel<<<grid, blk, 0, stream>>>(votes, act, Mu, A,
                                                    num_part, den_part, rsum_part);
        float* mo = (it == 2) ? Mu_out : Mu;
        float* ao = (it == 2) ? A_out  : A;
        finalize_kernel<<<NB, NO, 0, stream>>>(num_part, den_part, rsum_part, mo, ao);
    }
}